// Round 20
// baseline (525.430 us; speedup 1.0000x reference)
//
#include <hip/hip_runtime.h>
#include <hip/hip_bf16.h>
#include <math.h>

// Problem constants
constexpr int kB   = 2;
constexpr int kT   = 2048;
constexpr int kH   = 16;
constexpr int kC   = 64;    // chunk size
constexpr int kNc  = 32;    // T / C
constexpr int kM   = kB * kT;   // 4096
constexpr int kK   = 1024;

using bf16x8 = __attribute__((ext_vector_type(8))) short;
using f32x4  = __attribute__((ext_vector_type(4))) float;

__device__ __forceinline__ void glds16(const void* g, void* l) {
  __builtin_amdgcn_global_load_lds(
      (const __attribute__((address_space(1))) unsigned int*)g,
      (__attribute__((address_space(3))) unsigned int*)l, 16, 0, 0);
}

__device__ __forceinline__ float bf2f(unsigned short u) {
  union { unsigned int i; float f; } x;
  x.i = ((unsigned int)u) << 16;
  return x.f;
}

// ---------------------------------------------------------------------------
// bf16 MFMA NT-GEMM tile body, BK=32 DOUBLE-BUFFERED (2-phase template:
// STAGE(next) -> compute(cur) -> vmcnt0+barrier -> swap). The prefetched
// global_load_lds for tile t+1 are in flight during tile t's MFMA, so the
// end-of-iteration drain is overlapped. MFMA order = BK=32 steps ascending
// (identical to the BK=64 two-substep order) -> bit-identical output.
// LDS: 4 buffers (A0,B0,A1,B1 @ 8KB) inside a 33KB union with MODE5's Ct.
// MODE: 0 f32 plain; 3 beta/dec sigmoid packed; 4 softplus(Lp*x);
//       5 silu + kv pack (Ct epilogue); 6 q pack; 7 og bf16 plain.
// ---------------------------------------------------------------------------
template <int MODE>
__device__ __forceinline__ void gemm_body(
    const __hip_bfloat16* __restrict__ A, const __hip_bfloat16* __restrict__ W,
    void* outA, void* outB, int N, const float* Lp,
    const int bm, const int bn,
    __hip_bfloat16* sbuf, __hip_bfloat16* Ct) {
  const int tid = threadIdx.x;
  const int w = tid >> 6, lane = tid & 63;

  const int sr = tid >> 2, sp = tid & 3;
  const int g0 = sp ^ ((sr >> 1) & 3);
  const __hip_bfloat16* a0 = A + (size_t)(bm + sr) * kK + g0 * 8;
  const __hip_bfloat16* a1 = A + (size_t)(bm + sr + 64) * kK + g0 * 8;
  const __hip_bfloat16* b0 = W + (size_t)(bn + sr) * kK + g0 * 8;
  const __hip_bfloat16* b1 = W + (size_t)(bn + sr + 64) * kK + g0 * 8;

  __hip_bfloat16* Acur = sbuf;
  __hip_bfloat16* Bcur = sbuf + 4096;
  __hip_bfloat16* Anxt = sbuf + 8192;
  __hip_bfloat16* Bnxt = sbuf + 12288;
  const int wofs = w * 1024;

  const int wr = w >> 1, wc = w & 1;
  const int fr = lane & 15, fc = lane >> 4;
  int aOff[4], bOff[4];
#pragma unroll
  for (int f = 0; f < 4; f++) {
    const int ra = wr * 64 + f * 16 + fr;
    aOff[f] = ra * 64 + ((fc ^ ((ra >> 1) & 3)) * 16);
    const int rb = wc * 64 + f * 16 + fr;
    bOff[f] = rb * 64 + ((fc ^ ((rb >> 1) & 3)) * 16);
  }

  f32x4 acc[4][4];
#pragma unroll
  for (int i = 0; i < 4; i++)
#pragma unroll
    for (int j = 0; j < 4; j++) acc[i][j] = (f32x4){0.f, 0.f, 0.f, 0.f};

  // prologue: stage k0=0 into cur buffers, drain
  glds16(a0, (char*)Acur + wofs);
  glds16(a1, (char*)Acur + wofs + 4096);
  glds16(b0, (char*)Bcur + wofs);
  glds16(b1, (char*)Bcur + wofs + 4096);
  __syncthreads();

  for (int k0 = 0; k0 < kK; k0 += 32) {
    // issue prefetch of next K-tile (lands before this iteration's barrier)
    if (k0 + 32 < kK) {
      glds16(a0 + k0 + 32, (char*)Anxt + wofs);
      glds16(a1 + k0 + 32, (char*)Anxt + wofs + 4096);
      glds16(b0 + k0 + 32, (char*)Bnxt + wofs);
      glds16(b1 + k0 + 32, (char*)Bnxt + wofs + 4096);
    }

    bf16x8 af[4], bfr[4];
#pragma unroll
    for (int f = 0; f < 4; f++) af[f] = *(const bf16x8*)((const char*)Acur + aOff[f]);
#pragma unroll
    for (int f = 0; f < 4; f++) bfr[f] = *(const bf16x8*)((const char*)Bcur + bOff[f]);
#pragma unroll
    for (int i = 0; i < 4; i++)
#pragma unroll
      for (int j = 0; j < 4; j++)
        acc[i][j] = __builtin_amdgcn_mfma_f32_16x16x32_bf16(af[i], bfr[j], acc[i][j], 0, 0, 0);

    __syncthreads();   // drains prefetch loads + orders buffer reuse
    __hip_bfloat16* t0 = Acur; Acur = Anxt; Anxt = t0;
    __hip_bfloat16* t1 = Bcur; Bcur = Bnxt; Bnxt = t1;
  }

  if constexpr (MODE == 5) {
    // Ct aliases the staging buffers: K-loop ended with a barrier, safe.
#pragma unroll
    for (int i = 0; i < 4; i++)
#pragma unroll
      for (int j = 0; j < 4; j++)
#pragma unroll
        for (int e = 0; e < 4; e++) {
          const int rl = wr * 64 + i * 16 + fc * 4 + e;
          const int cl = wc * 64 + j * 16 + fr;
          float vx = acc[i][j][e];
          vx = vx / (1.f + expf(-vx));
          Ct[rl * 129 + cl] = __float2bfloat16(vx);
        }
    __syncthreads();
    const int cc0 = bn;
    const int hh0 = cc0 / 192;
    const int dl = tid & 31, rq = tid >> 5;
    for (int cmb = 0; cmb < 6; cmb++) {
      const int hh = hh0 + cmb / 3;
      if (hh >= 16) continue;
      const int j3 = cmb % 3;
      const int off = cc0 - hh * 192 - j3;     // cc = hh*192 + 3d + j3
      const int d_lo = (off <= 0) ? 0 : (off + 2) / 3;
      const int hi_num = off + 127;
      if (hi_num < 0) continue;
      const int d_hi = (hi_num / 3) > 63 ? 63 : (hi_num / 3);
      if (d_hi < d_lo) continue;
      for (int r0 = 0; r0 < 128; r0 += 8) {
        const int rl = r0 + rq;
        const int token = bm + rl;
        const int b = token >> 11, tok = token & 2047, chn = tok >> 6, tt = tok & 63;
        __hip_bfloat16* dst = (__hip_bfloat16*)outA +
            (size_t)((b * 16 + hh) * 32 + chn) * 12288 + (tt * 3 + j3) * 64;
        for (int dd = d_lo + dl; dd <= d_hi; dd += 32)
          dst[dd] = Ct[rl * 129 + hh * 192 + 3 * dd + j3 - cc0];
      }
    }
    return;
  }

  const int r0 = bm + wr * 64, c0 = bn + wc * 64;
#pragma unroll
  for (int i = 0; i < 4; i++)
#pragma unroll
    for (int j = 0; j < 4; j++)
#pragma unroll
      for (int e = 0; e < 4; e++) {
        const int rr = r0 + i * 16 + fc * 4 + e;
        const int cc = c0 + j * 16 + fr;
        float vx = acc[i][j][e];
        if constexpr (MODE == 0) {
          ((float*)outA)[(size_t)rr * N + cc] = vx;
        } else if constexpr (MODE == 4) {
          const float y = Lp[cc] * vx;
          vx = fmaxf(y, 0.f) + log1pf(expf(-fabsf(y)));
          ((float*)outA)[(size_t)rr * N + cc] = vx;
        } else if constexpr (MODE == 3) {
          const float s = 1.f / (1.f + expf(-vx));
          const int b = rr >> 11, tok = rr & 2047, chn = tok >> 6, tt = tok & 63;
          if (cc < 48) {
            const int hh = cc / 3, j3 = cc - hh * 3;
            ((float*)outA)[(size_t)((b * 16 + hh) * 32 + chn) * 192 + tt * 3 + j3] = s;
          } else if (cc < 64) {
            const int hh = cc - 48;
            ((float*)outB)[(size_t)((b * 16 + hh) * 32 + chn) * 64 + tt] = s;
          }
        } else if constexpr (MODE == 6) {
          const int b = rr >> 11, tok = rr & 2047, chn = tok >> 6, tt = tok & 63;
          const int hh = cc >> 6, d = cc & 63;
          ((__hip_bfloat16*)outA)[(size_t)((b * 16 + hh) * 32 + chn) * 4096 +
                                  tt * 64 + d] = __float2bfloat16(vx);
        } else if constexpr (MODE == 7) {
          ((__hip_bfloat16*)outA)[(size_t)rr * 1024 + cc] = __float2bfloat16(vx);
        }
      }
}

// ---------------------------------------------------------------------------
// gemm_fused: all six input projections in one dispatch (block-range -> mode).
// LDS: 33 KB union (4 x 8KB dbuf staging | Ct in the MODE5 epilogue).
// ---------------------------------------------------------------------------
__global__ __launch_bounds__(256) void gemm_fused(
    const __hip_bfloat16* __restrict__ xb,
    const __hip_bfloat16* __restrict__ Wqb, const __hip_bfloat16* __restrict__ Wkb,
    const __hip_bfloat16* __restrict__ Wvb, const __hip_bfloat16* __restrict__ Wbdb,
    const __hip_bfloat16* __restrict__ Wlb, const __hip_bfloat16* __restrict__ Wgb,
    __hip_bfloat16* qpack, __hip_bfloat16* KP16, __hip_bfloat16* VP16,
    float* betp, float* decp, float* lwb, __hip_bfloat16* ogb,
    const float* __restrict__ Lp) {
  __shared__ __hip_bfloat16 sbuf[128 * 129];   // 33,024 B union
  __hip_bfloat16* Ct = sbuf;
  const int id = blockIdx.x;
  if (id < 768) {
    const int l = id;
    gemm_body<5>(xb, Wkb, KP16, nullptr, 3072, nullptr, (l / 24) * 128, (l % 24) * 128,
                 sbuf, Ct);
  } else if (id < 1536) {
    const int l = id - 768;
    gemm_body<5>(xb, Wvb, VP16, nullptr, 3072, nullptr, (l / 24) * 128, (l % 24) * 128,
                 sbuf, Ct);
  } else if (id < 1792) {
    const int l = id - 1536;
    gemm_body<6>(xb, Wqb, qpack, nullptr, 1024, nullptr, (l >> 3) * 128, (l & 7) * 128,
                 sbuf, Ct);
  } else if (id < 2048) {
    const int l = id - 1792;
    gemm_body<7>(xb, Wgb, ogb, nullptr, 1024, nullptr, (l >> 3) * 128, (l & 7) * 128,
                 sbuf, Ct);
  } else if (id < 2080) {
    const int l = id - 2048;
    gemm_body<3>(xb, Wbdb, betp, decp, 128, nullptr, l * 128, 0, sbuf, Ct);
  } else {
    const int l = id - 2080;
    gemm_body<4>(xb, Wlb, lwb, nullptr, 256, Lp, (l >> 1) * 128, (l & 1) * 128,
                 sbuf, Ct);
  }
}

// gemm_out: final output projection (MODE 0), standalone (depends on gate).
__global__ __launch_bounds__(256) void gemm_out(
    const __hip_bfloat16* __restrict__ A, const __hip_bfloat16* __restrict__ W,
    float* __restrict__ out) {
  __shared__ __hip_bfloat16 sbuf[16384];   // 32 KB dbuf staging
  gemm_body<0>(A, W, out, nullptr, 1024, nullptr,
               blockIdx.y * 128, blockIdx.x * 128, sbuf, nullptr);
}

// ---------------------------------------------------------------------------
// cast_all: fused f32->bf16 casts for x + all weights + packed Wb/Wa tile.
// ---------------------------------------------------------------------------
__global__ void cast_all(const float* __restrict__ x, const float* __restrict__ Wq,
                         const float* __restrict__ Wk, const float* __restrict__ Wv,
                         const float* __restrict__ Wg, const float* __restrict__ Wl,
                         const float* __restrict__ Wo, const float* __restrict__ Wb,
                         const float* __restrict__ Wa,
                         __hip_bfloat16* __restrict__ xb, __hip_bfloat16* __restrict__ Wqb,
                         __hip_bfloat16* __restrict__ Wkb, __hip_bfloat16* __restrict__ Wvb,
                         __hip_bfloat16* __restrict__ Wgb, __hip_bfloat16* __restrict__ Wlb,
                         __hip_bfloat16* __restrict__ Wob, __hip_bfloat16* __restrict__ Wbdb) {
  const int gb = blockIdx.x, tid = threadIdx.x;
  const float* src; __hip_bfloat16* dst; int base;
  if (gb < 4096)       { src = x;  dst = xb;  base = gb; }
  else if (gb < 5120)  { src = Wq; dst = Wqb; base = gb - 4096; }
  else if (gb < 8192)  { src = Wk; dst = Wkb; base = gb - 5120; }
  else if (gb < 11264) { src = Wv; dst = Wvb; base = gb - 8192; }
  else if (gb < 12288) { src = Wg; dst = Wgb; base = gb - 11264; }
  else if (gb < 12544) { src = Wl; dst = Wlb; base = gb - 12288; }
  else if (gb < 13568) { src = Wo; dst = Wob; base = gb - 12544; }
  else {
    const int idx = (gb - 13568) * 256 + tid;
    if (idx < 128 * 1024) {
      const int r = idx >> 10, k = idx & 1023;
      const float val = (r < 48) ? Wb[r * 1024 + k]
                                 : ((r < 64) ? Wa[(r - 48) * 1024 + k] : 0.f);
      Wbdb[idx] = __float2bfloat16(val);
    }
    return;
  }
  const int i = (base * 256 + tid) * 4;
  const float4 v = *(const float4*)(src + i);
  __hip_bfloat16 tmp[4] = {__float2bfloat16(v.x), __float2bfloat16(v.y),
                           __float2bfloat16(v.z), __float2bfloat16(v.w)};
  *(ushort4*)(dst + i) = *(ushort4*)tmp;
}

__global__ void lwc_mean(const float* __restrict__ lw, float* __restrict__ lwc) {
  const int idx = blockIdx.x * 256 + threadIdx.x;
  if (idx >= kB * kNc * kH * 16) return;
  const int l = idx & 15, h = (idx >> 4) & 15, c = (idx >> 8) & 31, b = idx >> 13;
  size_t base = ((size_t)b * kT + (size_t)c * kC) * 256 + h * 16 + l;
  float s = 0.f;
  for (int tt = 0; tt < kC; tt++) s += lw[base + (size_t)tt * 256];
  lwc[idx] = s * (1.f / 64.f);
}

// ---------------------------------------------------------------------------
// gram_phi: per-chunk-head. S = [K(192); Q(64)] (256x64 bf16). Out = S*K^T.
// G tiles are stored PRE-SCALED by beta_j: G16[i][j] = bf16(beta_j*(k_i.k_j)).
// ---------------------------------------------------------------------------
__global__ __launch_bounds__(256, 1) void gram_phi(
    const __hip_bfloat16* __restrict__ KP16, const __hip_bfloat16* __restrict__ qpack,
    const float* __restrict__ betp,
    __hip_bfloat16* __restrict__ G16, __hip_bfloat16* __restrict__ Astk) {
  const int ch = blockIdx.x;
  const int tid = threadIdx.x;
  const int w = tid >> 6, lane = tid & 63;
  __shared__ __hip_bfloat16 Sa[256 * 64];  // row-swizzled
  __shared__ float betS[192];

  if (tid < 192) betS[tid] = betp[(size_t)ch * 192 + tid];
  for (int cidx = tid; cidx < 2048; cidx += 256) {
    const int r = cidx >> 3, cko = cidx & 7;
    const __hip_bfloat16* src =
        (r < 192) ? (KP16 + (size_t)ch * 12288 + r * 64 + cko * 8)
                  : (qpack + (size_t)ch * 4096 + (r - 192) * 64 + cko * 8);
    bf16x8 vv = *(const bf16x8*)src;
    *(bf16x8*)((char*)Sa + r * 128 + ((cko ^ ((r >> 1) & 3)) * 16)) = vv;
  }
  __syncthreads();

  const int fr = lane & 15, fc = lane >> 4;
  f32x4 acc[4][12];
#pragma unroll
  for (int i = 0; i < 4; i++)
#pragma unroll
    for (int j = 0; j < 12; j++) acc[i][j] = (f32x4){0.f, 0.f, 0.f, 0.f};

#pragma unroll
  for (int ks = 0; ks < 2; ks++) {
    bf16x8 af[4];
#pragma unroll
    for (int i = 0; i < 4; i++) {
      const int ra = w * 64 + i * 16 + fr;
      af[i] = *(const bf16x8*)((char*)Sa + ra * 128 + (((ks * 4 + fc) ^ ((ra >> 1) & 3)) * 16));
    }
#pragma unroll
    for (int j = 0; j < 12; j++) {
      const int rb = j * 16 + fr;
      bf16x8 bfv = *(const bf16x8*)((char*)Sa + rb * 128 + (((ks * 4 + fc) ^ ((rb >> 1) & 3)) * 16));
#pragma unroll
      for (int i = 0; i < 4; i++)
        acc[i][j] = __builtin_amdgcn_mfma_f32_16x16x32_bf16(af[i], bfv, acc[i][j], 0, 0, 0);
    }
  }

#pragma unroll
  for (int i = 0; i < 4; i++)
#pragma unroll
    for (int j = 0; j < 12; j++)
#pragma unroll
      for (int e = 0; e < 4; e++) {
        const int gr = w * 64 + i * 16 + fc * 4 + e;
        const int gc = j * 16 + fr;
        const float val = acc[i][j][e];
        if (gr < 192) {
          const int sbb = gr >> 6, jbb = gc >> 6;
          if (jbb <= sbb)
            G16[(size_t)ch * 24576 + (size_t)(sbb * (sbb + 1) / 2 + jbb) * 4096 +
                (gr & 63) * 64 + (gc & 63)] = __float2bfloat16(val * betS[gc]);
        } else {
          const int t = gr - 192;
          const float mval = ((gc / 3) <= t) ? val : 0.f;
          Astk[(size_t)ch * 24576 + (size_t)(64 + t) * 192 + gc] = __float2bfloat16(mval);
        }
      }

  // KT rows: Astk[ch][d][i] = K[i][d] (from swizzled LDS)
  for (int s = tid; s < 1536; s += 256) {
    const int d = s / 24, i0 = (s % 24) * 8;
    __hip_bfloat16 tmp[8];
#pragma unroll
    for (int e = 0; e < 8; e++) {
      const int i = i0 + e;
      tmp[e] = *(const __hip_bfloat16*)((char*)Sa + i * 128 +
                                        (((d >> 3) ^ ((i >> 1) & 3)) * 16) + (d & 7) * 2);
    }
    *(bf16x8*)(Astk + (size_t)ch * 24576 + (size_t)d * 192 + i0) = *(bf16x8*)tmp;
  }
}

// ---------------------------------------------------------------------------
// chunk_solve: grid (1024, 2). Block (ch, half) solves (I + Ltil) Xt = Rt for
// its 64-column half (half 0: K, half 1: V/c). G16 is PRE-SCALED by beta_j.
// 4x4 register-blocked updates; fma order k-ascending. In-place Bt write safe.
// ---------------------------------------------------------------------------
__global__ __launch_bounds__(256) void chunk_solve(
    const __hip_bfloat16* __restrict__ G16,
    __hip_bfloat16* __restrict__ KP16, __hip_bfloat16* __restrict__ VP16,
    const float* __restrict__ betp, const float* __restrict__ decp) {
  const int ch = blockIdx.x;
  const int half = blockIdx.y;
  const int tid = threadIdx.x;
  constexpr int XS = 68;   // X row stride (rows 16B-aligned; bank = 4r+c)
  __shared__ float X[192 * XS];      // 52,224 B
  __shared__ float bet[192], cpre[64], rc[64];

  if (tid < 192) bet[tid] = betp[(size_t)ch * 192 + tid];
  if (tid < 64) cpre[tid] = decp[(size_t)ch * 64 + tid];
  __syncthreads();
  if (tid == 0) {
    float p = 1.f;
    for (int t = 0; t < 64; t++) { p *= cpre[t]; cpre[t] = p; }
  }
  __syncthreads();
  if (tid < 64) rc[tid] = 1.f / cpre[tid];
  __syncthreads();

  // stage RHS (this half's 64 columns): half 0 -> K, half 1 -> V / c_tau(i)
  __hip_bfloat16* rhs = (half ? VP16 : KP16) + (size_t)ch * 12288;
  for (int v = tid; v < 1536; v += 256) {
    const int i = v >> 3, d0 = (v & 7) * 8;
    bf16x8 vb8 = *(const bf16x8*)(rhs + i * 64 + d0);
    const float sc = half ? rc[i / 3] : 1.f;
#pragma unroll
    for (int e = 0; e < 8; e++)
      X[i * XS + d0 + e] = __bfloat162float(*(((const __hip_bfloat16*)&vb8) + e)) * sc;
  }
  __syncthreads();

  const int ty = tid >> 4, tx = tid & 15;   // 16 x 16 thread grid
  const int col4 = tx * 4;
  const __hip_bfloat16* Gch = G16 + (size_t)ch * 24576;

  for (int sb = 0; sb < 3; sb++) {
    const int s = sb * 64;
    // ---- off-diagonal rank-64 updates (4x4 register blocked, G pre-scaled)
    for (int jb = 0; jb < sb; jb++) {
      const __hip_bfloat16* gt = Gch + (size_t)(sb * (sb + 1) / 2 + jb) * 4096;
      const int j0 = jb * 64;
      const int r0 = s + ty * 4;
      float4 acc[4];
#pragma unroll
      for (int r = 0; r < 4; r++) acc[r] = *(const float4*)&X[(r0 + r) * XS + col4];
#pragma unroll
      for (int k4 = 0; k4 < 16; k4++) {
        float4 xv[4];
#pragma unroll
        for (int e = 0; e < 4; e++)
          xv[e] = *(const float4*)&X[(j0 + k4 * 4 + e) * XS + col4];
#pragma unroll
        for (int r = 0; r < 4; r++) {
          const ushort4 g4 = *(const ushort4*)(gt + (ty * 4 + r) * 64 + k4 * 4);
          float4 t;
          t.x = bf2f(g4.x);
          t.y = bf2f(g4.y);
          t.z = bf2f(g4.z);
          t.w = bf2f(g4.w);
          acc[r].x = fmaf(-t.x, xv[0].x, acc[r].x);
          acc[r].y = fmaf(-t.x, xv[0].y, acc[r].y);
          acc[r].z = fmaf(-t.x, xv[0].z, acc[r].z);
          acc[r].w = fmaf(-t.x, xv[0].w, acc[r].w);
          acc[r].x = fmaf(-t.y, xv[1].x, acc[r].x);
          acc[r].y = fmaf(-t.y, xv[1].y, acc[r].y);
          acc[r].z = fmaf(-t.y, xv[1].z, acc[r].z);
          acc[r].w = fmaf(-t.y, xv[1].w, acc[r].w);
          acc[r].x = fmaf(-t.z, xv[2].x, acc[r].x);
          acc[r].y = fmaf(-t.z, xv[2].y, acc[r].y);
          acc[r].z = fmaf(-t.z, xv[2].z, acc[r].z);
          acc[r].w = fmaf(-t.z, xv[2].w, acc[r].w);
          acc[r].x = fmaf(-t.w, xv[3].x, acc[r].x);
          acc[r].y = fmaf(-t.w, xv[3].y, acc[r].y);
          acc[r].z = fmaf(-t.w, xv[3].z, acc[r].z);
          acc[r].w = fmaf(-t.w, xv[3].w, acc[r].w);
        }
      }
#pragma unroll
      for (int r = 0; r < 4; r++) *(float4*)&X[(r0 + r) * XS + col4] = acc[r];
      __syncthreads();
    }

    // ---- 16-sub-blocked diagonal solve (G pre-scaled)
    const __hip_bfloat16* gd = Gch + (size_t)(sb * (sb + 1) / 2 + sb) * 4096;
    for (int db = 0; db < 4; db++) {
      const int l0 = db * 16;
      if (tid < 64) {  // one wave: serial 16-row solve entirely in registers
        float xd[16];
#pragma unroll
        for (int j = 0; j < 16; j++) xd[j] = X[(s + l0 + j) * XS + tid];
#pragma unroll
        for (int ii = 1; ii < 16; ii++)
          for (int jj = 0; jj < ii; jj++) {
            const float t = bf2f(*(const unsigned short*)(gd + (l0 + ii) * 64 + l0 + jj));
            xd[ii] = fmaf(-t, xd[jj], xd[ii]);
          }
#pragma unroll
        for (int j = 1; j < 16; j++) X[(s + l0 + j) * XS + tid] = xd[j];
      }
      __syncthreads();
      // trailing rank-16 update on rows l0+16..63 (4x4 register blocked)
      const int rem = 48 - l0;
      if (rem > 0) {
        const int ng = rem >> 2;   // row-groups of 4: 12, 8, 4
        if (ty < ng) {
          const int r0 = s + l0 + 16 + ty * 4;
          float4 acc[4];
#pragma unroll
          for (int r = 0; r < 4; r++) acc[r] = *(const float4*)&X[(r0 + r) * XS + col4];
#pragma unroll
          for (int k4 = 0; k4 < 4; k4++) {
            float4 xv[4];
#pragma unroll
            for (int e = 0; e < 4; e++)
              xv[e] = *(const float4*)&X[(s + l0 + k4 * 4 + e) * XS + col4];
#pragma unroll
            for (int r = 0; r < 4; r++) {
              const ushort4 g4 =
                  *(const ushort4*)(gd + (l0 + 16 + ty * 4 + r) * 64 + l0 + k4 * 4);
              float4 t;
              t.x = bf2f(g4.x);
              t.y = bf2f(g4.y);
              t.z = bf2f(g4.z);
              t.w = bf2f(g4.w);
              acc[r].x = fmaf(-t.x, xv[0].x, acc[r].x);
              acc[r].y = fmaf(-t.x, xv[0].y, acc[r].y);
              acc[r].z = fmaf(-t.x, xv[0].z, acc[r].z);
              acc[r].w = fmaf(-t.x, xv[0].w, acc[r].w);
              acc[r].x = fmaf(-t.y, xv[1].x, acc[r].x);
              acc[r].y = fmaf(-t.y, xv[1].y, acc[r].y);
              acc[r].z = fmaf(-t.y, xv[1].z, acc[r].z);
              acc[r].w = fmaf(-t.y, xv[1].w, acc[r].w);
              acc[r].x = fmaf(-t.z, xv[2].x, acc[r].x);
              acc[r].y = fmaf(-t.z, xv[2].y, acc[r].y);
              acc[r].z = fmaf(-t.z, xv[2].z, acc[r].z);
              acc[r].w = fmaf(-t.z, xv[2].w, acc[r].w);
              acc[r].x = fmaf(-t.w, xv[3].x, acc[r].x);
              acc[r].y = fmaf(-t.w, xv[3].y, acc[r].y);
              acc[r].z = fmaf(-t.w, xv[3].z, acc[r].z);
              acc[r].w = fmaf(-t.w, xv[3].w, acc[r].w);
            }
          }
#pragma unroll
          for (int r = 0; r < 4; r++) *(float4*)&X[(r0 + r) * XS + col4] = acc[r];
        }
      }
      __syncthreads();
    }
  }

  // ---- write Bt over this half's strip: Bt[col][i] = beta_i * X[i][col]
  for (int v = tid; v < 1536; v += 256) {
    const int c2 = v & 63, i0 = (v >> 6) * 8;
    __hip_bfloat16 tmp[8];
#pragma unroll
    for (int e = 0; e < 8; e++)
      tmp[e] = __float2bfloat16(bet[i0 + e] * X[(i0 + e) * XS + c2]);
    *(bf16x8*)(rhs + c2 * 192 + i0) = *(bf16x8*)tmp;
  }
}

// ---------------------------------------------------------------------------
// products: per ch. Out(128x128) = Astk(128x192) x Bt(128x192)^T-NT.
// K-loop double-buffered (same 2-phase template as gemm_body).
// ---------------------------------------------------------------------------
__global__ __launch_bounds__(256) void products(
    const __hip_bfloat16* __restrict__ Astk,
    const __hip_bfloat16* __restrict__ KP16, const __hip_bfloat16* __restrict__ VP16,
    const __hip_bfloat16* __restrict__ qpack, const float* __restrict__ decp,
    float* __restrict__ Tc, float* __restrict__ Qe,
    float* __restrict__ BcW, float* __restrict__ VoW) {
  const int ch = blockIdx.x;
  const int tid = threadIdx.x;
  const int w = tid >> 6, lane = tid & 63;
  __shared__ __hip_bfloat16 sbuf[16384];   // 4 x 8KB dbuf staging
  __shared__ float cpre[64];

  if (tid < 64) cpre[tid] = decp[(size_t)ch * 64 + tid];
  __syncthreads();
  if (tid == 0) {
    float p = 1.f;
    for (int t = 0; t < 64; t++) { p *= cpre[t]; cpre[t] = p; }
  }

  const int sr = tid >> 2, sp = tid & 3;
  const int g0 = sp ^ ((sr >> 1) & 3);
  const __hip_bfloat16* a0 = Astk + (size_t)ch * 24576 + sr * 192 + g0 * 8;
  const __hip_bfloat16* a1 = a0 + 64 * 192;
  const __hip_bfloat16* b0 = KP16 + (size_t)ch * 12288 + sr * 192 + g0 * 8;
  const __hip_bfloat16* b1 = VP16 + (size_t)ch * 12288 + sr * 192 + g0 * 8;

  __hip_bfloat16* Acur = sbuf;
  __hip_bfloat16* Bcur = sbuf + 4096;
  __hip_bfloat16* Anxt = sbuf + 8192;
  __hip_bfloat16* Bnxt = sbuf + 12288;
  const int wofs = w * 1024;

  const int wr = w >> 1, wc = w & 1;
  const int fr = lane & 15, fc = lane >> 4;
  int aOff[4], bOff[4];
#pragma unroll
  for (int f = 0; f < 4; f++) {
    const int ra = wr * 64 + f * 16 + fr;
    aOff[f] = ra * 64 + ((fc ^ ((ra >> 1) & 3)) * 16);
    const int rb = wc * 64 + f * 16 + fr;
    bOff[f] = rb * 64 + ((fc ^ ((rb >> 1) & 3)) * 16);
  }

  f32x4 acc[4][4];
#pragma unroll
  for (int i = 0; i < 4; i++)
#pragma unroll
    for (int j = 0; j < 4; j++) acc[i][j] = (f32x4){0.f, 0.f, 0.f, 0.f};

  glds16(a0, (char*)Acur + wofs);
  glds16(a1, (char*)Acur + wofs + 4096);
  glds16(b0, (char*)Bcur + wofs);
  glds16(b1, (char*)Bcur + wofs + 4096);
  __syncthreads();

  for (int k0 = 0; k0 < 192; k0 += 32) {
    if (k0 + 32 < 192) {
      glds16(a0 + k0 + 32, (char*)Anxt + wofs);
      glds16(a1 + k0 + 32, (char*)Anxt + wofs + 4096);
      glds16(b0 + k0 + 32, (char*)Bnxt + wofs);
      glds16(b1 + k0 + 32, (char*)Bnxt + wofs + 4096);
    }

    bf16x8 af[4], bfr[4];
#pragma unroll
    for (int f = 0; f < 4; f++) af[f] = *(const bf16x8*)((const char*)Acur + aOff[f]);
#pragma unroll
    for (int f = 0; f < 4; f++) bfr[f] = *(const bf16x8*)((const char*)Bcur + bOff[f]);
#pragma unroll
    for (int i = 0; i < 4; i++)
#pragma unroll
      for (int j = 0; j < 4; j++)
        acc[i][j] = __builtin_amdgcn_mfma_f32_16x16x32_bf16(af[i], bfr[j], acc[i][j], 0, 0, 0);

    __syncthreads();
    __hip_bfloat16* t0 = Acur; Acur = Anxt; Anxt = t0;
    __hip_bfloat16* t1 = Bcur; Bcur = Bnxt; Bnxt = t1;
  }

  const float cC = cpre[63];
#pragma unroll
  for (int i = 0; i < 4; i++)
#pragma unroll
    for (int j = 0; j < 4; j++)
#pragma unroll
      for (int e = 0; e < 4; e++) {
        const int rr = wr * 64 + i * 16 + fc * 4 + e;
        const int cc = wc * 64 + j * 16 + fr;
        const float val = acc[i][j][e];
        if (rr < 64) {
          if (cc < 64)
            Tc[(size_t)ch * 4096 + rr * 64 + cc] = cC * (((rr == cc) ? 1.f : 0.f) - val);
          else
            BcW[(size_t)ch * 6144 + rr * 64 + (cc - 64)] = cC * val;
        } else {
          const int t = rr - 64;
          const float ct = cpre[t];
          if (cc < 64) {
            const float qv = __bfloat162float(qpack[(size_t)ch * 4096 + t * 64 + cc]);
            Qe[(size_t)ch * 4096 + t * 64 + cc] = ct * (qv - val);
          } else {
            VoW[(size_t)ch * 6144 + t * 64 + (cc - 64)] = ct * val;
          }
        }
      }
}

// ---------------------------------------------------------------------------
// state_scan: 256 blocks = (b,h) x 8 v-slices. Sequential state pass only.
// ---------------------------------------------------------------------------
__global__ __launch_bounds__(256) void state_scan(
    const float* __restrict__ Tc, const float* __restrict__ BcS,
    const float* __restrict__ lwcb, float* __restrict__ S0g) {
  const int blk = blockIdx.x;       // bh*8 + vs
  const int bh = blk >> 3, vs = blk & 7;
  const int b = bh >> 4, h = bh & 15;
  const int vbase = vs * 8;
  const int tid = threadIdx.x;
  const int v = tid & 7;
  const int tg = tid >> 3;          // 0..31

  __shared__ float stL[6][64][8];
  __shared__ float S0s[8][68];
  __shared__ float Tt[64][68];
  __shared__ float Bt_[64][8];

  for (int idx = tid; idx < 6 * 512; idx += 256) ((float*)stL)[idx] = 0.f;

  float tReg[16], bReg[2];
  {
    const size_t ch0 = (size_t)bh * 32;
#pragma unroll
    for (int i = 0; i < 16; i++) tReg[i] = Tc[ch0 * 4096 + tid + i * 256];
#pragma unroll
    for (int i = 0; i < 2; i++) {
      const int idx = tid + i * 256;
      bReg[i] = BcS[ch0 * 6144 + (idx >> 3) * 64 + vbase + (idx & 7)];
    }
  }
  __syncthreads();

  for (int c = 0; c < 32; c++) {
    const size_t ch = (size_t)bh * 32 + c;
#pragma unroll
    for (int i = 0; i < 16; i++) {
      const int idx = tid + i * 256;
      Tt[idx >> 6][idx & 63] = tReg[i];
    }
#pragma unroll
    for (int i = 0; i < 2; i++) {
      const int idx = tid + i * 256;
      Bt_[idx >> 3][idx & 7] = bReg[i];
    }

    const float* lwp = lwcb + ((size_t)(b * kNc + c) * kH + h) * 16;
    float lw[6];
#pragma unroll
    for (int l = 0; l < 6; l++) lw[l] = lwp[l];
#pragma unroll
    for (int n = 0; n < 2; n++) {
      const int k = n * 32 + tg;
      float s = 0.f;
#pragma unroll
      for (int l = 0; l < 6; l++) s = fmaf(lw[l], stL[l][k][v], s);
      S0s[v][k] = s;
      S0g[ch * 4096 + k * 64 + vbase + v] = s;
    }
    __syncthreads();

    const size_t chn = (size_t)bh * 32 + (c < 31 ? c + 1 : 31);
#pragma unroll
    for (int i = 0; i < 16; i++) tReg[i] = Tc[chn * 4096 + tid + i * 256];
#pragma unroll
    for (int i = 0; i < 2; i++) {
      const int idx = tid + i * 256;
      bReg[i] = BcS[chn * 6144 + (idx >> 3) * 64 + vbase + (idx & 7)];
    }

    const int lev = __builtin_ctz(c + 1);
#pragma unroll
    for (int n = 0; n < 2; n++) {
      const int r = n * 32 + tg;
      float s = Bt_[r][v];
#pragma unroll
      for (int k4 = 0; k4 < 16; k4++) {
        const float4 t4 = *(const float4*)&Tt[r][k4 * 4];
        const float4 s4 = *(const float4*)&S0s[v][k4 * 4];
        s = fmaf(t4.x, s4.x, s);
        s = fmaf(t4.y, s4.y, s);
        s = fmaf(t4.z, s4.z, s);
        s = fmaf(t4.w, s4.w, s);
      }
      for (int l = 0; l < lev; l++) { s += stL[l][r][v]; stL[l][r][v] = 0.f; }
      stL[lev][r][v] = s;
    }
    __syncthreads();
  }
}

// ---------------------------------------------------------------------------
// o_gemm: 1024 parallel blocks. O = Qe * S0 + Vo, with fused per-ch groupnorm
// partial sums (double, fixed tree order -> deterministic).
// ---------------------------------------------------------------------------
__global__ __launch_bounds__(256) void o_gemm(
    const float* __restrict__ Qe, const float* __restrict__ S0g,
    const float* __restrict__ VoS, float* __restrict__ Obuf,
    double* __restrict__ part) {
  const int ch = blockIdx.x;
  const int tid = threadIdx.x;
  const int v = tid & 63;
  const int tg = tid >> 6;  // 0..3
  __shared__ float Qs[64][64];
  __shared__ float Ss[64][64];
  __shared__ double sred[256], qred[256];
  for (int idx = tid; idx < 4096; idx += 256) {
    ((float*)Qs)[idx] = Qe[(size_t)ch * 4096 + idx];
    ((float*)Ss)[idx] = S0g[(size_t)ch * 4096 + idx];
  }
  __syncthreads();
  double psum = 0.0, psq = 0.0;
#pragma unroll
  for (int n = 0; n < 16; n++) {
    const int t = n * 4 + tg;
    float o = VoS[(size_t)ch * 6144 + t * 64 + v];
#pragma unroll 8
    for (int k = 0; k < 64; k++) o = fmaf(Qs[t][k], Ss[k][v], o);
    Obuf[(size_t)ch * 4096 + t * 64 + v] = o;
    psum += o;
    psq += (double)o * o;
  }
  sred[tid] = psum;
  qred[tid] = psq;
  __syncthreads();
  for (int stp = 128; stp > 0; stp >>= 1) {
    if (tid < stp) {
      sred[tid] += sred[tid + stp];
      qred[tid] += qred[tid + stp];
    }
    __syncthreads();
  }
  if (tid == 0) {
    part[ch * 2] = sred[0];
    part[ch * 2 + 1] = qred[0];
  }
}

// ---------------------------------------------------------------------------
// gn_stats2: final deterministic reduction (32 chunk-partials per (b,h)).
// ---------------------------------------------------------------------------
__global__ void gn_stats2(const double* __restrict__ part, float* __restrict__ stats) {
  const int bh = threadIdx.x;
  if (bh >= 32) return;
  double s = 0.0, qq = 0.0;
  for (int i = 0; i < 32; i++) {
    s += part[(bh * 32 + i) * 2];
    qq += part[(bh * 32 + i) * 2 + 1];
  }
  const double n = (double)kT * 64.0;
  const double mu = s / n;
  const double var = qq / n - mu * mu;
  stats[bh * 2] = (float)mu;
  stats[bh * 2 + 1] = (float)(1.0 / sqrt(var + 1e-5));
}

__global__ void gate_kernel(const float* __restrict__ Obuf,
                            const __hip_bfloat16* __restrict__ og,
                            const float* __restrict__ gamma, const float* __restrict__ gbeta,
                            const float* __restrict__ stats, __hip_bfloat16* __restrict__ z) {
  const size_t idx = (size_t)blockIdx.x * 256 + threadIdx.x;
  if (idx >= (size_t)kM * 1024) return;
  const int cidx = (int)(idx & 1023);
  const int h = cidx >> 6, v = cidx & 63;
  const size_t m = idx >> 10;
  const int b = (int)(m >> 11);
  const int tok = (int)(m & 2047), c = tok >> 6, tt = tok & 63;
  const float o = Obuf[(size_t)((b * 16 + h) * 32 + c) * 4096 + tt * 64 + v];
  const float mu = stats[(b * 16 + h) * 2];
  const float rstd = stats[(b * 16 + h) * 2 + 1];
  const float val = (o - mu) * rstd * gamma[cidx] + gbeta[cidx];
  const float gt = __bfloat162float(og[idx]);
  z[idx] = __float2bfloat16(val * (1.f / (1.f + expf(-gt))));
}

// ---------------------------------------------------------------------------
extern "C" void kernel_launch(void* const* d_in, const int* in_sizes, int n_in,
                              void* d_out, int out_size, void* d_ws, size_t ws_size,
                              hipStream_t stream) {
  const float* x     = (const float*)d_in[0];
  const float* Wq    = (const float*)d_in[3];
  const float* Wk    = (const float*)d_in[4];
  const float* Wv    = (const float*)d_in[5];
  const float* Wb    = (const float*)d_in[6];
  const float* Wa    = (const float*)d_in[7];
  const float* Wg    = (const float*)d_in[8];
  const float* Wo    = (const float*)d_in[9];
  const float* Wl    = (const float*)d_in[10];
  const float* Lp    = (const float*)d_in[11];
  const float* gamma = (const float*)d_in[12];
  const float* gbeta = (const float*)d_in[13];
  float* out = (float*)d_out;
  (void)ws_size;  // peak usage < 181,469,440 proven in round 1

  char* base = (char*)d_ws;
  // P1: qpack -> zbf
  __hip_bfloat16* qpack = (__hip_bfloat16*)(base + 0);                 // 8,388,608
  __hip_bfloat16* zbf   = qpack;                                       // after products
  // P2/P3: kv packs -> Bt (in-place) -> Bc/Vo f32 (in-place)
  __hip_bfloat16* KP16 = (__hip_bfloat16*)(base + 8388608);            // 25,165,824
  __hip_bfloat16* VP16 = (__hip_bfloat16*)(base + 33554432);           // 25,165,824
  // P4 region (50,331,648): early = xb + weights; then G16; then Tc/Qe/Obuf
  char* P4 = base + 58720256;
  __hip_bfloat16* xb   = (__hip_bfloat16*)(P4 + 0);                    // 8,388,608
  __hip_bfloat16* Wqb  = (__hip_bfloat16*)(P4 + 8388608);              // 2,097,152
  __hip_bfloat16* Wkb  = (__hip_bfloat16*)(P4 + 10485760);             // 6,291,456
  __hip_bfloat16* Wvb  = (__hip_bfloat16*)(P4 + 16777216);             // 6,291,456
  __hip_bfloat16* Wgb  = (__hip_bfloat16*)(P4 + 23068672);             // 2,097,152
  __hip_bfloat16* Wlb  = (__hip_bfloat16*)(P4 + 25165824);             // 524,288
  __hip_bfloat16* Wbdb = (__hip_bfloat16*)(P4 + 25690112);             // 262,144
  __hip_bfloat16* G16  = (__hip_bfloat16*)P4;                          // full 50,331,648
  float* Tc   = (float*)(P4 + 0);                                      // 16,777,216
  float* Qe   = (float*)(P4 + 16777216);                               // 16,777,216
  float* Obuf = (float*)(P4 + 33554432);                               // 16,777,216
  // P5 region (50,331,648): early = lwb; then Astk; then S0g (Astk dead)
  char* P5 = base + 109051904;
  float* lwb = (float*)(P5 + 0);                                       // 4,194,304
  __hip_bfloat16* Astk = (__hip_bfloat16*)P5;                          // 50,331,648
  float* S0g = (float*)P5;                                             // 16,777,216
  // P6: persistent small
  char* P6 = base + 159383552;
  float* betp  = (float*)(P6 + 0);                                     // 786,432
  float* decp  = (float*)(P6 + 786432);                                // 262,144
  float* lwcb  = (float*)(P6 + 1048576);                               // 65,536
  float* statb = (float*)(P6 + 1114112);                               // 1,024
  __hip_bfloat16* Wob = (__hip_bfloat16*)(P6 + 1115136);               // 2,097,152
  __hip_bfloat16* ogb = (__hip_bfloat16*)(P6 + 3212288);               // 8,388,608
  double* gnpart = (double*)(base + 170984448);                        // 16,384

  const dim3 blk(256);

  // fused casts (x + all weights + bd pack)
  cast_all<<<dim3(14080), blk, 0, stream>>>(x, Wq, Wk, Wv, Wg, Wl, Wo, Wb, Wa,
                                            xb, Wqb, Wkb, Wvb, Wgb, Wlb, Wob, Wbdb);

  // all six input projections in one dispatch
  gemm_fused<<<dim3(2144), blk, 0, stream>>>(xb, Wqb, Wkb, Wvb, Wbdb, Wlb, Wgb,
                                             qpack, KP16, VP16, betp, decp, lwb, ogb, Lp);

  lwc_mean<<<dim3(64), blk, 0, stream>>>(lwb, lwcb);

  // chunk operators
  gram_phi<<<dim3(1024), blk, 0, stream>>>(KP16, qpack, betp, G16, Astk);
  chunk_solve<<<dim3(1024, 2), blk, 0, stream>>>(G16, KP16, VP16, betp, decp);
  products<<<dim3(1024), blk, 0, stream>>>(Astk, KP16, VP16, qpack, decp,
                                           Tc, Qe, (float*)KP16, (float*)VP16);

  // sequential state scan (256 blocks) + parallel O gemm (+ fused gn partials)
  state_scan<<<dim3(256), blk, 0, stream>>>(Tc, (const float*)KP16, lwcb, S0g);
  o_gemm<<<dim3(1024), blk, 0, stream>>>(Qe, S0g, (const float*)VP16, Obuf, gnpart);

  // group norm + gate
  gn_stats2<<<dim3(1), dim3(64), 0, stream>>>(gnpart, statb);
  gate_kernel<<<dim3((kM * 1024 + 255) / 256), blk, 0, stream>>>(Obuf, ogb, gamma, gbeta,
                                                                 statb, zbf);

  // final projection
  gemm_out<<<dim3(8, 32), blk, 0, stream>>>(zbf, Wob, out);
}

// Round 21
// 513.014 us; speedup vs baseline: 1.0242x; 1.0242x over previous
//
#include <hip/hip_runtime.h>
#include <hip/hip_bf16.h>
#include <math.h>

// Problem constants
constexpr int kB   = 2;
constexpr int kT   = 2048;
constexpr int kH   = 16;
constexpr int kC   = 64;    // chunk size
constexpr int kNc  = 32;    // T / C
constexpr int kM   = kB * kT;   // 4096
constexpr int kK   = 1024;

using bf16x8 = __attribute__((ext_vector_type(8))) short;
using f32x4  = __attribute__((ext_vector_type(4))) float;

__device__ __forceinline__ void glds16(const void* g, void* l) {
  __builtin_amdgcn_global_load_lds(
      (const __attribute__((address_space(1))) unsigned int*)g,
      (__attribute__((address_space(3))) unsigned int*)l, 16, 0, 0);
}

__device__ __forceinline__ float bf2f(unsigned short u) {
  union { unsigned int i; float f; } x;
  x.i = ((unsigned int)u) << 16;
  return x.f;
}

// ---------------------------------------------------------------------------
// bf16 MFMA NT-GEMM tile body, BK=64 (verified round-19 structure). MODE:
//  0: f32 plain [rr*N+cc]
//  3: beta(48)/dec(16) sigmoid -> betp [ch][192] f32, decp [ch][64] f32
//  4: softplus(Lp*x) f32 plain (lw)
//  5: silu -> bf16 pack [ch][i=tt*3+j3][d], coalesced via LDS tile epilogue
//  6: bf16 q pack [ch][t][d]
//  7: bf16 plain [rr*1024+cc] (og)
// ---------------------------------------------------------------------------
template <int MODE>
__device__ __forceinline__ void gemm_body(
    const __hip_bfloat16* __restrict__ A, const __hip_bfloat16* __restrict__ W,
    void* outA, void* outB, int N, const float* Lp,
    const int bm, const int bn,
    __hip_bfloat16* As, __hip_bfloat16* Bs, __hip_bfloat16* Ct) {
  const int tid = threadIdx.x;
  const int w = tid >> 6, lane = tid & 63;

  // staging map (BK=64, rows of 128 B = 8 x 16B chunks):
  // call i, wave w, lane l -> LDS byte i*4096 + w*1024 + l*16
  //   => row = i*32 + w*8 + (l>>3), physical chunk = l&7.
  // logical chunk = pch ^ ((row>>1)&7); (row+32)>>1 & 7 == (row>>1)&7, so one
  // gch serves all 4 calls.
  const int rb  = w * 8 + (lane >> 3);          // row base 0..31
  const int gch = (lane & 7) ^ ((rb >> 1) & 7);
  const __hip_bfloat16* aSrc = A + (size_t)(bm + rb) * kK + gch * 8;
  const __hip_bfloat16* bSrc = W + (size_t)(bn + rb) * kK + gch * 8;

  const int wr = w >> 1, wc = w & 1;
  const int fr = lane & 15, fc = lane >> 4;
  int aBase[4], bBase[4], aSw[4], bSw[4];
#pragma unroll
  for (int f = 0; f < 4; f++) {
    const int ra = wr * 64 + f * 16 + fr;
    aBase[f] = ra * 128;
    aSw[f] = (ra >> 1) & 7;
    const int rbb = wc * 64 + f * 16 + fr;
    bBase[f] = rbb * 128;
    bSw[f] = (rbb >> 1) & 7;
  }

  f32x4 acc[4][4];
#pragma unroll
  for (int i = 0; i < 4; i++)
#pragma unroll
    for (int j = 0; j < 4; j++) acc[i][j] = (f32x4){0.f, 0.f, 0.f, 0.f};

  for (int k0 = 0; k0 < kK; k0 += 64) {
    __syncthreads();
#pragma unroll
    for (int i = 0; i < 4; i++)
      glds16(aSrc + (size_t)(i * 32) * kK + k0, (char*)As + i * 4096 + w * 1024);
#pragma unroll
    for (int i = 0; i < 4; i++)
      glds16(bSrc + (size_t)(i * 32) * kK + k0, (char*)Bs + i * 4096 + w * 1024);
    __syncthreads();

#pragma unroll
    for (int ks = 0; ks < 2; ks++) {
      bf16x8 af[4], bfr[4];
#pragma unroll
      for (int f = 0; f < 4; f++)
        af[f] = *(const bf16x8*)((const char*)As + aBase[f] +
                                 (((ks * 4 + fc) ^ aSw[f]) * 16));
#pragma unroll
      for (int f = 0; f < 4; f++)
        bfr[f] = *(const bf16x8*)((const char*)Bs + bBase[f] +
                                  (((ks * 4 + fc) ^ bSw[f]) * 16));
#pragma unroll
      for (int i = 0; i < 4; i++)
#pragma unroll
        for (int j = 0; j < 4; j++)
          acc[i][j] = __builtin_amdgcn_mfma_f32_16x16x32_bf16(af[i], bfr[j], acc[i][j], 0, 0, 0);
    }
  }

  if constexpr (MODE == 5) {
    // Ct aliases As/Bs: ensure every wave is done with the K-loop LDS reads
    __syncthreads();
    // stage silu'd tile in LDS, then write destination-major coalesced runs
#pragma unroll
    for (int i = 0; i < 4; i++)
#pragma unroll
      for (int j = 0; j < 4; j++)
#pragma unroll
        for (int e = 0; e < 4; e++) {
          const int rl = wr * 64 + i * 16 + fc * 4 + e;
          const int cl = wc * 64 + j * 16 + fr;
          float vx = acc[i][j][e];
          vx = vx / (1.f + expf(-vx));
          Ct[rl * 129 + cl] = __float2bfloat16(vx);
        }
    __syncthreads();
    const int cc0 = bn;
    const int hh0 = cc0 / 192;
    const int dl = tid & 31, rq = tid >> 5;
    for (int cmb = 0; cmb < 6; cmb++) {
      const int hh = hh0 + cmb / 3;
      if (hh >= 16) continue;
      const int j3 = cmb % 3;
      const int off = cc0 - hh * 192 - j3;     // cc = hh*192 + 3d + j3
      const int d_lo = (off <= 0) ? 0 : (off + 2) / 3;
      const int hi_num = off + 127;
      if (hi_num < 0) continue;
      const int d_hi = (hi_num / 3) > 63 ? 63 : (hi_num / 3);
      if (d_hi < d_lo) continue;
      for (int r0 = 0; r0 < 128; r0 += 8) {
        const int rl = r0 + rq;
        const int token = bm + rl;
        const int b = token >> 11, tok = token & 2047, chn = tok >> 6, tt = tok & 63;
        __hip_bfloat16* dst = (__hip_bfloat16*)outA +
            (size_t)((b * 16 + hh) * 32 + chn) * 12288 + (tt * 3 + j3) * 64;
        for (int dd = d_lo + dl; dd <= d_hi; dd += 32)
          dst[dd] = Ct[rl * 129 + hh * 192 + 3 * dd + j3 - cc0];
      }
    }
    return;
  }

  const int r0 = bm + wr * 64, c0 = bn + wc * 64;
#pragma unroll
  for (int i = 0; i < 4; i++)
#pragma unroll
    for (int j = 0; j < 4; j++)
#pragma unroll
      for (int e = 0; e < 4; e++) {
        const int rr = r0 + i * 16 + fc * 4 + e;
        const int cc = c0 + j * 16 + fr;
        float vx = acc[i][j][e];
        if constexpr (MODE == 0) {
          ((float*)outA)[(size_t)rr * N + cc] = vx;
        } else if constexpr (MODE == 4) {
          const float y = Lp[cc] * vx;
          vx = fmaxf(y, 0.f) + log1pf(expf(-fabsf(y)));
          ((float*)outA)[(size_t)rr * N + cc] = vx;
        } else if constexpr (MODE == 3) {
          const float s = 1.f / (1.f + expf(-vx));
          const int b = rr >> 11, tok = rr & 2047, chn = tok >> 6, tt = tok & 63;
          if (cc < 48) {
            const int hh = cc / 3, j3 = cc - hh * 3;
            ((float*)outA)[(size_t)((b * 16 + hh) * 32 + chn) * 192 + tt * 3 + j3] = s;
          } else if (cc < 64) {
            const int hh = cc - 48;
            ((float*)outB)[(size_t)((b * 16 + hh) * 32 + chn) * 64 + tt] = s;
          }
        } else if constexpr (MODE == 6) {
          const int b = rr >> 11, tok = rr & 2047, chn = tok >> 6, tt = tok & 63;
          const int hh = cc >> 6, d = cc & 63;
          ((__hip_bfloat16*)outA)[(size_t)((b * 16 + hh) * 32 + chn) * 4096 +
                                  tt * 64 + d] = __float2bfloat16(vx);
        } else if constexpr (MODE == 7) {
          ((__hip_bfloat16*)outA)[(size_t)rr * 1024 + cc] = __float2bfloat16(vx);
        }
      }
}

// ---------------------------------------------------------------------------
// gemm_fused: all six input projections in one dispatch (block-range -> mode).
// Small modes (3,4) dispatch FIRST so they don't straggle the tail; the long
// K/V ranges fill the final scheduling wave. LDS: 33 KB union (As|Bs 16 KB
// each during the K-loop; Ct in the MODE5 epilogue).
// ---------------------------------------------------------------------------
__global__ __launch_bounds__(256) void gemm_fused(
    const __hip_bfloat16* __restrict__ xb,
    const __hip_bfloat16* __restrict__ Wqb, const __hip_bfloat16* __restrict__ Wkb,
    const __hip_bfloat16* __restrict__ Wvb, const __hip_bfloat16* __restrict__ Wbdb,
    const __hip_bfloat16* __restrict__ Wlb, const __hip_bfloat16* __restrict__ Wgb,
    __hip_bfloat16* qpack, __hip_bfloat16* KP16, __hip_bfloat16* VP16,
    float* betp, float* decp, float* lwb, __hip_bfloat16* ogb,
    const float* __restrict__ Lp) {
  __shared__ __hip_bfloat16 sbuf[128 * 129];   // 33,024 B union
  __hip_bfloat16* As = sbuf;                   // 16,384 B (K-loop)
  __hip_bfloat16* Bs = sbuf + 128 * 64;        // 16,384 B (K-loop)
  __hip_bfloat16* Ct = sbuf;                   // 33,024 B (MODE5 epilogue)
  const int id = blockIdx.x;
  if (id < 32) {
    gemm_body<3>(xb, Wbdb, betp, decp, 128, nullptr, id * 128, 0, As, Bs, Ct);
  } else if (id < 96) {
    const int l = id - 32;
    gemm_body<4>(xb, Wlb, lwb, nullptr, 256, Lp, (l >> 1) * 128, (l & 1) * 128,
                 As, Bs, Ct);
  } else if (id < 352) {
    const int l = id - 96;
    gemm_body<6>(xb, Wqb, qpack, nullptr, 1024, nullptr, (l >> 3) * 128, (l & 7) * 128,
                 As, Bs, Ct);
  } else if (id < 608) {
    const int l = id - 352;
    gemm_body<7>(xb, Wgb, ogb, nullptr, 1024, nullptr, (l >> 3) * 128, (l & 7) * 128,
                 As, Bs, Ct);
  } else if (id < 1376) {
    const int l = id - 608;
    gemm_body<5>(xb, Wkb, KP16, nullptr, 3072, nullptr, (l / 24) * 128, (l % 24) * 128,
                 As, Bs, Ct);
  } else {
    const int l = id - 1376;
    gemm_body<5>(xb, Wvb, VP16, nullptr, 3072, nullptr, (l / 24) * 128, (l % 24) * 128,
                 As, Bs, Ct);
  }
}

// gemm_out: final output projection (MODE 0), standalone (depends on gate).
__global__ __launch_bounds__(256) void gemm_out(
    const __hip_bfloat16* __restrict__ A, const __hip_bfloat16* __restrict__ W,
    float* __restrict__ out) {
  __shared__ __hip_bfloat16 As[128 * 64];
  __shared__ __hip_bfloat16 Bs[128 * 64];
  gemm_body<0>(A, W, out, nullptr, 1024, nullptr,
               blockIdx.y * 128, blockIdx.x * 128, As, Bs, nullptr);
}

// ---------------------------------------------------------------------------
// cast_all: fused f32->bf16 casts for x + all weights + packed Wb/Wa tile.
// ---------------------------------------------------------------------------
__global__ void cast_all(const float* __restrict__ x, const float* __restrict__ Wq,
                         const float* __restrict__ Wk, const float* __restrict__ Wv,
                         const float* __restrict__ Wg, const float* __restrict__ Wl,
                         const float* __restrict__ Wo, const float* __restrict__ Wb,
                         const float* __restrict__ Wa,
                         __hip_bfloat16* __restrict__ xb, __hip_bfloat16* __restrict__ Wqb,
                         __hip_bfloat16* __restrict__ Wkb, __hip_bfloat16* __restrict__ Wvb,
                         __hip_bfloat16* __restrict__ Wgb, __hip_bfloat16* __restrict__ Wlb,
                         __hip_bfloat16* __restrict__ Wob, __hip_bfloat16* __restrict__ Wbdb) {
  const int gb = blockIdx.x, tid = threadIdx.x;
  const float* src; __hip_bfloat16* dst; int base;
  if (gb < 4096)       { src = x;  dst = xb;  base = gb; }
  else if (gb < 5120)  { src = Wq; dst = Wqb; base = gb - 4096; }
  else if (gb < 8192)  { src = Wk; dst = Wkb; base = gb - 5120; }
  else if (gb < 11264) { src = Wv; dst = Wvb; base = gb - 8192; }
  else if (gb < 12288) { src = Wg; dst = Wgb; base = gb - 11264; }
  else if (gb < 12544) { src = Wl; dst = Wlb; base = gb - 12288; }
  else if (gb < 13568) { src = Wo; dst = Wob; base = gb - 12544; }
  else {
    const int idx = (gb - 13568) * 256 + tid;
    if (idx < 128 * 1024) {
      const int r = idx >> 10, k = idx & 1023;
      const float val = (r < 48) ? Wb[r * 1024 + k]
                                 : ((r < 64) ? Wa[(r - 48) * 1024 + k] : 0.f);
      Wbdb[idx] = __float2bfloat16(val);
    }
    return;
  }
  const int i = (base * 256 + tid) * 4;
  const float4 v = *(const float4*)(src + i);
  __hip_bfloat16 tmp[4] = {__float2bfloat16(v.x), __float2bfloat16(v.y),
                           __float2bfloat16(v.z), __float2bfloat16(v.w)};
  *(ushort4*)(dst + i) = *(ushort4*)tmp;
}

__global__ void lwc_mean(const float* __restrict__ lw, float* __restrict__ lwc) {
  const int idx = blockIdx.x * 256 + threadIdx.x;
  if (idx >= kB * kNc * kH * 16) return;
  const int l = idx & 15, h = (idx >> 4) & 15, c = (idx >> 8) & 31, b = idx >> 13;
  size_t base = ((size_t)b * kT + (size_t)c * kC) * 256 + h * 16 + l;
  float s = 0.f;
  for (int tt = 0; tt < kC; tt++) s += lw[base + (size_t)tt * 256];
  lwc[idx] = s * (1.f / 64.f);
}

// ---------------------------------------------------------------------------
// gram_phi: per-chunk-head. S = [K(192); Q(64)] (256x64 bf16). Out = S*K^T.
// G tiles are stored PRE-SCALED by beta_j: G16[i][j] = bf16(beta_j*(k_i.k_j)).
// ---------------------------------------------------------------------------
__global__ __launch_bounds__(256, 1) void gram_phi(
    const __hip_bfloat16* __restrict__ KP16, const __hip_bfloat16* __restrict__ qpack,
    const float* __restrict__ betp,
    __hip_bfloat16* __restrict__ G16, __hip_bfloat16* __restrict__ Astk) {
  const int ch = blockIdx.x;
  const int tid = threadIdx.x;
  const int w = tid >> 6, lane = tid & 63;
  __shared__ __hip_bfloat16 Sa[256 * 64];  // row-swizzled
  __shared__ float betS[192];

  if (tid < 192) betS[tid] = betp[(size_t)ch * 192 + tid];
  for (int cidx = tid; cidx < 2048; cidx += 256) {
    const int r = cidx >> 3, cko = cidx & 7;
    const __hip_bfloat16* src =
        (r < 192) ? (KP16 + (size_t)ch * 12288 + r * 64 + cko * 8)
                  : (qpack + (size_t)ch * 4096 + (r - 192) * 64 + cko * 8);
    bf16x8 vv = *(const bf16x8*)src;
    *(bf16x8*)((char*)Sa + r * 128 + ((cko ^ ((r >> 1) & 3)) * 16)) = vv;
  }
  __syncthreads();

  const int fr = lane & 15, fc = lane >> 4;
  f32x4 acc[4][12];
#pragma unroll
  for (int i = 0; i < 4; i++)
#pragma unroll
    for (int j = 0; j < 12; j++) acc[i][j] = (f32x4){0.f, 0.f, 0.f, 0.f};

#pragma unroll
  for (int ks = 0; ks < 2; ks++) {
    bf16x8 af[4];
#pragma unroll
    for (int i = 0; i < 4; i++) {
      const int ra = w * 64 + i * 16 + fr;
      af[i] = *(const bf16x8*)((char*)Sa + ra * 128 + (((ks * 4 + fc) ^ ((ra >> 1) & 3)) * 16));
    }
#pragma unroll
    for (int j = 0; j < 12; j++) {
      const int rb = j * 16 + fr;
      bf16x8 bfv = *(const bf16x8*)((char*)Sa + rb * 128 + (((ks * 4 + fc) ^ ((rb >> 1) & 3)) * 16));
#pragma unroll
      for (int i = 0; i < 4; i++)
        acc[i][j] = __builtin_amdgcn_mfma_f32_16x16x32_bf16(af[i], bfv, acc[i][j], 0, 0, 0);
    }
  }

#pragma unroll
  for (int i = 0; i < 4; i++)
#pragma unroll
    for (int j = 0; j < 12; j++)
#pragma unroll
      for (int e = 0; e < 4; e++) {
        const int gr = w * 64 + i * 16 + fc * 4 + e;
        const int gc = j * 16 + fr;
        const float val = acc[i][j][e];
        if (gr < 192) {
          const int sbb = gr >> 6, jbb = gc >> 6;
          if (jbb <= sbb)
            G16[(size_t)ch * 24576 + (size_t)(sbb * (sbb + 1) / 2 + jbb) * 4096 +
                (gr & 63) * 64 + (gc & 63)] = __float2bfloat16(val * betS[gc]);
        } else {
          const int t = gr - 192;
          const float mval = ((gc / 3) <= t) ? val : 0.f;
          Astk[(size_t)ch * 24576 + (size_t)(64 + t) * 192 + gc] = __float2bfloat16(mval);
        }
      }

  // KT rows: Astk[ch][d][i] = K[i][d] (from swizzled LDS)
  for (int s = tid; s < 1536; s += 256) {
    const int d = s / 24, i0 = (s % 24) * 8;
    __hip_bfloat16 tmp[8];
#pragma unroll
    for (int e = 0; e < 8; e++) {
      const int i = i0 + e;
      tmp[e] = *(const __hip_bfloat16*)((char*)Sa + i * 128 +
                                        (((d >> 3) ^ ((i >> 1) & 3)) * 16) + (d & 7) * 2);
    }
    *(bf16x8*)(Astk + (size_t)ch * 24576 + (size_t)d * 192 + i0) = *(bf16x8*)tmp;
  }
}

// ---------------------------------------------------------------------------
// chunk_solve: grid (1024, 2). Block (ch, half) solves (I + Ltil) Xt = Rt for
// its 64-column half (half 0: K, half 1: V/c). G16 is PRE-SCALED by beta_j.
// 4x4 register-blocked updates; fma order k-ascending. In-place Bt write safe.
// ---------------------------------------------------------------------------
__global__ __launch_bounds__(256) void chunk_solve(
    const __hip_bfloat16* __restrict__ G16,
    __hip_bfloat16* __restrict__ KP16, __hip_bfloat16* __restrict__ VP16,
    const float* __restrict__ betp, const float* __restrict__ decp) {
  const int ch = blockIdx.x;
  const int half = blockIdx.y;
  const int tid = threadIdx.x;
  constexpr int XS = 68;   // X row stride (rows 16B-aligned; bank = 4r+c)
  __shared__ float X[192 * XS];      // 52,224 B
  __shared__ float bet[192], cpre[64], rc[64];

  if (tid < 192) bet[tid] = betp[(size_t)ch * 192 + tid];
  if (tid < 64) cpre[tid] = decp[(size_t)ch * 64 + tid];
  __syncthreads();
  if (tid == 0) {
    float p = 1.f;
    for (int t = 0; t < 64; t++) { p *= cpre[t]; cpre[t] = p; }
  }
  __syncthreads();
  if (tid < 64) rc[tid] = 1.f / cpre[tid];
  __syncthreads();

  // stage RHS (this half's 64 columns): half 0 -> K, half 1 -> V / c_tau(i)
  __hip_bfloat16* rhs = (half ? VP16 : KP16) + (size_t)ch * 12288;
  for (int v = tid; v < 1536; v += 256) {
    const int i = v >> 3, d0 = (v & 7) * 8;
    bf16x8 vb8 = *(const bf16x8*)(rhs + i * 64 + d0);
    const float sc = half ? rc[i / 3] : 1.f;
#pragma unroll
    for (int e = 0; e < 8; e++)
      X[i * XS + d0 + e] = __bfloat162float(*(((const __hip_bfloat16*)&vb8) + e)) * sc;
  }
  __syncthreads();

  const int ty = tid >> 4, tx = tid & 15;   // 16 x 16 thread grid
  const int col4 = tx * 4;
  const __hip_bfloat16* Gch = G16 + (size_t)ch * 24576;

  for (int sb = 0; sb < 3; sb++) {
    const int s = sb * 64;
    // ---- off-diagonal rank-64 updates (4x4 register blocked, G pre-scaled)
    for (int jb = 0; jb < sb; jb++) {
      const __hip_bfloat16* gt = Gch + (size_t)(sb * (sb + 1) / 2 + jb) * 4096;
      const int j0 = jb * 64;
      const int r0 = s + ty * 4;
      float4 acc[4];
#pragma unroll
      for (int r = 0; r < 4; r++) acc[r] = *(const float4*)&X[(r0 + r) * XS + col4];
#pragma unroll
      for (int k4 = 0; k4 < 16; k4++) {
        float4 xv[4];
#pragma unroll
        for (int e = 0; e < 4; e++)
          xv[e] = *(const float4*)&X[(j0 + k4 * 4 + e) * XS + col4];
#pragma unroll
        for (int r = 0; r < 4; r++) {
          const ushort4 g4 = *(const ushort4*)(gt + (ty * 4 + r) * 64 + k4 * 4);
          float4 t;
          t.x = bf2f(g4.x);
          t.y = bf2f(g4.y);
          t.z = bf2f(g4.z);
          t.w = bf2f(g4.w);
          acc[r].x = fmaf(-t.x, xv[0].x, acc[r].x);
          acc[r].y = fmaf(-t.x, xv[0].y, acc[r].y);
          acc[r].z = fmaf(-t.x, xv[0].z, acc[r].z);
          acc[r].w = fmaf(-t.x, xv[0].w, acc[r].w);
          acc[r].x = fmaf(-t.y, xv[1].x, acc[r].x);
          acc[r].y = fmaf(-t.y, xv[1].y, acc[r].y);
          acc[r].z = fmaf(-t.y, xv[1].z, acc[r].z);
          acc[r].w = fmaf(-t.y, xv[1].w, acc[r].w);
          acc[r].x = fmaf(-t.z, xv[2].x, acc[r].x);
          acc[r].y = fmaf(-t.z, xv[2].y, acc[r].y);
          acc[r].z = fmaf(-t.z, xv[2].z, acc[r].z);
          acc[r].w = fmaf(-t.z, xv[2].w, acc[r].w);
          acc[r].x = fmaf(-t.w, xv[3].x, acc[r].x);
          acc[r].y = fmaf(-t.w, xv[3].y, acc[r].y);
          acc[r].z = fmaf(-t.w, xv[3].z, acc[r].z);
          acc[r].w = fmaf(-t.w, xv[3].w, acc[r].w);
        }
      }
#pragma unroll
      for (int r = 0; r < 4; r++) *(float4*)&X[(r0 + r) * XS + col4] = acc[r];
      __syncthreads();
    }

    // ---- 16-sub-blocked diagonal solve (G pre-scaled)
    const __hip_bfloat16* gd = Gch + (size_t)(sb * (sb + 1) / 2 + sb) * 4096;
    for (int db = 0; db < 4; db++) {
      const int l0 = db * 16;
      if (tid < 64) {  // one wave: serial 16-row solve entirely in registers
        float xd[16];
#pragma unroll
        for (int j = 0; j < 16; j++) xd[j] = X[(s + l0 + j) * XS + tid];
#pragma unroll
        for (int ii = 1; ii < 16; ii++)
          for (int jj = 0; jj < ii; jj++) {
            const float t = bf2f(*(const unsigned short*)(gd + (l0 + ii) * 64 + l0 + jj));
            xd[ii] = fmaf(-t, xd[jj], xd[ii]);
          }
#pragma unroll
        for (int j = 1; j < 16; j++) X[(s + l0 + j) * XS + tid] = xd[j];
      }
      __syncthreads();
      // trailing rank-16 update on rows l0+16..63 (4x4 register blocked)
      const int rem = 48 - l0;
      if (rem > 0) {
        const int ng = rem >> 2;   // row-groups of 4: 12, 8, 4
        if (ty < ng) {
          const int r0 = s + l0 + 16 + ty * 4;
          float4 acc[4];
#pragma unroll
          for (int r = 0; r < 4; r++) acc[r] = *(const float4*)&X[(r0 + r) * XS + col4];
#pragma unroll
          for (int k4 = 0; k4 < 4; k4++) {
            float4 xv[4];
#pragma unroll
            for (int e = 0; e < 4; e++)
              xv[e] = *(const float4*)&X[(s + l0 + k4 * 4 + e) * XS + col4];
#pragma unroll
            for (int r = 0; r < 4; r++) {
              const ushort4 g4 =
                  *(const ushort4*)(gd + (l0 + 16 + ty * 4 + r) * 64 + l0 + k4 * 4);
              float4 t;
              t.x = bf2f(g4.x);
              t.y = bf2f(g4.y);
              t.z = bf2f(g4.z);
              t.w = bf2f(g4.w);
              acc[r].x = fmaf(-t.x, xv[0].x, acc[r].x);
              acc[r].y = fmaf(-t.x, xv[0].y, acc[r].y);
              acc[r].z = fmaf(-t.x, xv[0].z, acc[r].z);
              acc[r].w = fmaf(-t.x, xv[0].w, acc[r].w);
              acc[r].x = fmaf(-t.y, xv[1].x, acc[r].x);
              acc[r].y = fmaf(-t.y, xv[1].y, acc[r].y);
              acc[r].z = fmaf(-t.y, xv[1].z, acc[r].z);
              acc[r].w = fmaf(-t.y, xv[1].w, acc[r].w);
              acc[r].x = fmaf(-t.z, xv[2].x, acc[r].x);
              acc[r].y = fmaf(-t.z, xv[2].y, acc[r].y);
              acc[r].z = fmaf(-t.z, xv[2].z, acc[r].z);
              acc[r].w = fmaf(-t.z, xv[2].w, acc[r].w);
              acc[r].x = fmaf(-t.w, xv[3].x, acc[r].x);
              acc[r].y = fmaf(-t.w, xv[3].y, acc[r].y);
              acc[r].z = fmaf(-t.w, xv[3].z, acc[r].z);
              acc[r].w = fmaf(-t.w, xv[3].w, acc[r].w);
            }
          }
#pragma unroll
          for (int r = 0; r < 4; r++) *(float4*)&X[(r0 + r) * XS + col4] = acc[r];
        }
      }
      __syncthreads();
    }
  }

  // ---- write Bt over this half's strip: Bt[col][i] = beta_i * X[i][col]
  for (int v = tid; v < 1536; v += 256) {
    const int c2 = v & 63, i0 = (v >> 6) * 8;
    __hip_bfloat16 tmp[8];
#pragma unroll
    for (int e = 0; e < 8; e++)
      tmp[e] = __float2bfloat16(bet[i0 + e] * X[(i0 + e) * XS + c2]);
    *(bf16x8*)(rhs + c2 * 192 + i0) = *(bf16x8*)tmp;
  }
}

// ---------------------------------------------------------------------------
// products: per ch. Out(128x128) = Astk(128x192) x Bt(128x192)^T-NT.
// ---------------------------------------------------------------------------
__global__ __launch_bounds__(256) void products(
    const __hip_bfloat16* __restrict__ Astk,
    const __hip_bfloat16* __restrict__ KP16, const __hip_bfloat16* __restrict__ VP16,
    const __hip_bfloat16* __restrict__ qpack, const float* __restrict__ decp,
    float* __restrict__ Tc, float* __restrict__ Qe,
    float* __restrict__ BcW, float* __restrict__ VoW) {
  const int ch = blockIdx.x;
  const int tid = threadIdx.x;
  const int w = tid >> 6, lane = tid & 63;
  __shared__ __hip_bfloat16 As[128 * 32];
  __shared__ __hip_bfloat16 Bs[128 * 32];
  __shared__ float cpre[64];

  if (tid < 64) cpre[tid] = decp[(size_t)ch * 64 + tid];
  __syncthreads();
  if (tid == 0) {
    float p = 1.f;
    for (int t = 0; t < 64; t++) { p *= cpre[t]; cpre[t] = p; }
  }

  const int sr = tid >> 2, sp = tid & 3;
  const int g0 = sp ^ ((sr >> 1) & 3);
  const __hip_bfloat16* a0 = Astk + (size_t)ch * 24576 + sr * 192 + g0 * 8;
  const __hip_bfloat16* a1 = a0 + 64 * 192;
  const __hip_bfloat16* b0 = KP16 + (size_t)ch * 12288 + sr * 192 + g0 * 8;
  const __hip_bfloat16* b1 = VP16 + (size_t)ch * 12288 + sr * 192 + g0 * 8;
  char* AsB = (char*)As + w * 1024;
  char* BsB = (char*)Bs + w * 1024;

  const int wr = w >> 1, wc = w & 1;
  const int fr = lane & 15, fc = lane >> 4;
  int aOff[4], bOff[4];
#pragma unroll
  for (int f = 0; f < 4; f++) {
    const int ra = wr * 64 + f * 16 + fr;
    aOff[f] = ra * 64 + ((fc ^ ((ra >> 1) & 3)) * 16);
    const int rb = wc * 64 + f * 16 + fr;
    bOff[f] = rb * 64 + ((fc ^ ((rb >> 1) & 3)) * 16);
  }

  f32x4 acc[4][4];
#pragma unroll
  for (int i = 0; i < 4; i++)
#pragma unroll
    for (int j = 0; j < 4; j++) acc[i][j] = (f32x4){0.f, 0.f, 0.f, 0.f};

  for (int k0 = 0; k0 < 192; k0 += 32) {
    __syncthreads();
    glds16(a0 + k0, AsB);
    glds16(a1 + k0, AsB + 4096);
    glds16(b0 + k0, BsB);
    glds16(b1 + k0, BsB + 4096);
    __syncthreads();

    bf16x8 af[4], bfr[4];
#pragma unroll
    for (int f = 0; f < 4; f++) af[f] = *(const bf16x8*)((const char*)As + aOff[f]);
#pragma unroll
    for (int f = 0; f < 4; f++) bfr[f] = *(const bf16x8*)((const char*)Bs + bOff[f]);
#pragma unroll
    for (int i = 0; i < 4; i++)
#pragma unroll
      for (int j = 0; j < 4; j++)
        acc[i][j] = __builtin_amdgcn_mfma_f32_16x16x32_bf16(af[i], bfr[j], acc[i][j], 0, 0, 0);
  }
  __syncthreads();

  const float cC = cpre[63];
#pragma unroll
  for (int i = 0; i < 4; i++)
#pragma unroll
    for (int j = 0; j < 4; j++)
#pragma unroll
      for (int e = 0; e < 4; e++) {
        const int rr = wr * 64 + i * 16 + fc * 4 + e;
        const int cc = wc * 64 + j * 16 + fr;
        const float val = acc[i][j][e];
        if (rr < 64) {
          if (cc < 64)
            Tc[(size_t)ch * 4096 + rr * 64 + cc] = cC * (((rr == cc) ? 1.f : 0.f) - val);
          else
            BcW[(size_t)ch * 6144 + rr * 64 + (cc - 64)] = cC * val;
        } else {
          const int t = rr - 64;
          const float ct = cpre[t];
          if (cc < 64) {
            const float qv = __bfloat162float(qpack[(size_t)ch * 4096 + t * 64 + cc]);
            Qe[(size_t)ch * 4096 + t * 64 + cc] = ct * (qv - val);
          } else {
            VoW[(size_t)ch * 6144 + t * 64 + (cc - 64)] = ct * val;
          }
        }
      }
}

// ---------------------------------------------------------------------------
// state_scan: 256 blocks = (b,h) x 8 v-slices. Sequential state pass only.
// ---------------------------------------------------------------------------
__global__ __launch_bounds__(256) void state_scan(
    const float* __restrict__ Tc, const float* __restrict__ BcS,
    const float* __restrict__ lwcb, float* __restrict__ S0g) {
  const int blk = blockIdx.x;       // bh*8 + vs
  const int bh = blk >> 3, vs = blk & 7;
  const int b = bh >> 4, h = bh & 15;
  const int vbase = vs * 8;
  const int tid = threadIdx.x;
  const int v = tid & 7;
  const int tg = tid >> 3;          // 0..31

  __shared__ float stL[6][64][8];
  __shared__ float S0s[8][68];
  __shared__ float Tt[64][68];
  __shared__ float Bt_[64][8];

  for (int idx = tid; idx < 6 * 512; idx += 256) ((float*)stL)[idx] = 0.f;

  float tReg[16], bReg[2];
  {
    const size_t ch0 = (size_t)bh * 32;
#pragma unroll
    for (int i = 0; i < 16; i++) tReg[i] = Tc[ch0 * 4096 + tid + i * 256];
#pragma unroll
    for (int i = 0; i < 2; i++) {
      const int idx = tid + i * 256;
      bReg[i] = BcS[ch0 * 6144 + (idx >> 3) * 64 + vbase + (idx & 7)];
    }
  }
  __syncthreads();

  for (int c = 0; c < 32; c++) {
    const size_t ch = (size_t)bh * 32 + c;
#pragma unroll
    for (int i = 0; i < 16; i++) {
      const int idx = tid + i * 256;
      Tt[idx >> 6][idx & 63] = tReg[i];
    }
#pragma unroll
    for (int i = 0; i < 2; i++) {
      const int idx = tid + i * 256;
      Bt_[idx >> 3][idx & 7] = bReg[i];
    }

    const float* lwp = lwcb + ((size_t)(b * kNc + c) * kH + h) * 16;
    float lw[6];
#pragma unroll
    for (int l = 0; l < 6; l++) lw[l] = lwp[l];
#pragma unroll
    for (int n = 0; n < 2; n++) {
      const int k = n * 32 + tg;
      float s = 0.f;
#pragma unroll
      for (int l = 0; l < 6; l++) s = fmaf(lw[l], stL[l][k][v], s);
      S0s[v][k] = s;
      S0g[ch * 4096 + k * 64 + vbase + v] = s;
    }
    __syncthreads();

    const size_t chn = (size_t)bh * 32 + (c < 31 ? c + 1 : 31);
#pragma unroll
    for (int i = 0; i < 16; i++) tReg[i] = Tc[chn * 4096 + tid + i * 256];
#pragma unroll
    for (int i = 0; i < 2; i++) {
      const int idx = tid + i * 256;
      bReg[i] = BcS[chn * 6144 + (idx >> 3) * 64 + vbase + (idx & 7)];
    }

    const int lev = __builtin_ctz(c + 1);
#pragma unroll
    for (int n = 0; n < 2; n++) {
      const int r = n * 32 + tg;
      float s = Bt_[r][v];
#pragma unroll
      for (int k4 = 0; k4 < 16; k4++) {
        const float4 t4 = *(const float4*)&Tt[r][k4 * 4];
        const float4 s4 = *(const float4*)&S0s[v][k4 * 4];
        s = fmaf(t4.x, s4.x, s);
        s = fmaf(t4.y, s4.y, s);
        s = fmaf(t4.z, s4.z, s);
        s = fmaf(t4.w, s4.w, s);
      }
      for (int l = 0; l < lev; l++) { s += stL[l][r][v]; stL[l][r][v] = 0.f; }
      stL[lev][r][v] = s;
    }
    __syncthreads();
  }
}

// ---------------------------------------------------------------------------
// o_gemm: 1024 parallel blocks. O = Qe * S0 + Vo, with fused per-ch groupnorm
// partial sums (double, fixed tree order -> deterministic).
// ---------------------------------------------------------------------------
__global__ __launch_bounds__(256) void o_gemm(
    const float* __restrict__ Qe, const float* __restrict__ S0g,
    const float* __restrict__ VoS, float* __restrict__ Obuf,
    double* __restrict__ part) {
  const int ch = blockIdx.x;
  const int tid = threadIdx.x;
  const int v = tid & 63;
  const int tg = tid >> 6;  // 0..3
  __shared__ float Qs[64][64];
  __shared__ float Ss[64][64];
  __shared__ double sred[256], qred[256];
  for (int idx = tid; idx < 4096; idx += 256) {
    ((float*)Qs)[idx] = Qe[(size_t)ch * 4096 + idx];
    ((float*)Ss)[idx] = S0g[(size_t)ch * 4096 + idx];
  }
  __syncthreads();
  double psum = 0.0, psq = 0.0;
#pragma unroll
  for (int n = 0; n < 16; n++) {
    const int t = n * 4 + tg;
    float o = VoS[(size_t)ch * 6144 + t * 64 + v];
#pragma unroll 8
    for (int k = 0; k < 64; k++) o = fmaf(Qs[t][k], Ss[k][v], o);
    Obuf[(size_t)ch * 4096 + t * 64 + v] = o;
    psum += o;
    psq += (double)o * o;
  }
  sred[tid] = psum;
  qred[tid] = psq;
  __syncthreads();
  for (int stp = 128; stp > 0; stp >>= 1) {
    if (tid < stp) {
      sred[tid] += sred[tid + stp];
      qred[tid] += qred[tid + stp];
    }
    __syncthreads();
  }
  if (tid == 0) {
    part[ch * 2] = sred[0];
    part[ch * 2 + 1] = qred[0];
  }
}

// ---------------------------------------------------------------------------
// gn_stats2: final deterministic reduction (32 chunk-partials per (b,h)).
// ---------------------------------------------------------------------------
__global__ void gn_stats2(const double* __restrict__ part, float* __restrict__ stats) {
  const int bh = threadIdx.x;
  if (bh >= 32) return;
  double s = 0.0, qq = 0.0;
  for (int i = 0; i < 32; i++) {
    s += part[(bh * 32 + i) * 2];
    qq += part[(bh * 32 + i) * 2 + 1];
  }
  const double n = (double)kT * 64.0;
  const double mu = s / n;
  const double var = qq / n - mu * mu;
  stats[bh * 2] = (float)mu;
  stats[bh * 2 + 1] = (float)(1.0 / sqrt(var + 1e-5));
}

__global__ void gate_kernel(const float* __restrict__ Obuf,
                            const __hip_bfloat16* __restrict__ og,
                            const float* __restrict__ gamma, const float* __restrict__ gbeta,
                            const float* __restrict__ stats, __hip_bfloat16* __restrict__ z) {
  const size_t idx = (size_t)blockIdx.x * 256 + threadIdx.x;
  if (idx >= (size_t)kM * 1024) return;
  const int cidx = (int)(idx & 1023);
  const int h = cidx >> 6, v = cidx & 63;
  const size_t m = idx >> 10;
  const int b = (int)(m >> 11);
  const int tok = (int)(m & 2047), c = tok >> 6, tt = tok & 63;
  const float o = Obuf[(size_t)((b * 16 + h) * 32 + c) * 4096 + tt * 64 + v];
  const float mu = stats[(b * 16 + h) * 2];
  const float rstd = stats[(b * 16 + h) * 2 + 1];
  const float val = (o - mu) * rstd * gamma[cidx] + gbeta[cidx];
  const float gt = __bfloat162float(og[idx]);
  z[idx] = __float2bfloat16(val * (1.f / (1.f + expf(-gt))));
}

// ---------------------------------------------------------------------------
extern "C" void kernel_launch(void* const* d_in, const int* in_sizes, int n_in,
                              void* d_out, int out_size, void* d_ws, size_t ws_size,
                              hipStream_t stream) {
  const float* x     = (const float*)d_in[0];
  const float* Wq    = (const float*)d_in[3];
  const float* Wk    = (const float*)d_in[4];
  const float* Wv    = (const float*)d_in[5];
  const float* Wb    = (const float*)d_in[6];
  const float* Wa    = (const float*)d_in[7];
  const float* Wg    = (const float*)d_in[8];
  const float* Wo    = (const float*)d_in[9];
  const float* Wl    = (const float*)d_in[10];
  const float* Lp    = (const float*)d_in[11];
  const float* gamma = (const float*)d_in[12];
  const float* gbeta = (const float*)d_in[13];
  float* out = (float*)d_out;
  (void)ws_size;  // peak usage < 181,469,440 proven in round 1

  char* base = (char*)d_ws;
  // P1: qpack -> zbf
  __hip_bfloat16* qpack = (__hip_bfloat16*)(base + 0);                 // 8,388,608
  __hip_bfloat16* zbf   = qpack;                                       // after products
  // P2/P3: kv packs -> Bt (in-place) -> Bc/Vo f32 (in-place)
  __hip_bfloat16* KP16 = (__hip_bfloat16*)(base + 8388608);            // 25,165,824
  __hip_bfloat16* VP16 = (__hip_bfloat16*)(base + 33554432);           // 25,165,824
  // P4 region (50,331,648): early = xb + weights; then G16; then Tc/Qe/Obuf
  char* P4 = base + 58720256;
  __hip_bfloat16* xb   = (__hip_bfloat16*)(P4 + 0);                    // 8,388,608
  __hip_bfloat16* Wqb  = (__hip_bfloat16*)(P4 + 8388608);              // 2,097,152
  __hip_bfloat16* Wkb  = (__hip_bfloat16*)(P4 + 10485760);             // 6,291,456
  __hip_bfloat16* Wvb  = (__hip_bfloat16*)(P4 + 16777216);             // 6,291,456
  __hip_bfloat16* Wgb  = (__hip_bfloat16*)(P4 + 23068672);             // 2,097,152
  __hip_bfloat16* Wlb  = (__hip_bfloat16*)(P4 + 25165824);             // 524,288
  __hip_bfloat16* Wbdb = (__hip_bfloat16*)(P4 + 25690112);             // 262,144
  __hip_bfloat16* G16  = (__hip_bfloat16*)P4;                          // full 50,331,648
  float* Tc   = (float*)(P4 + 0);                                      // 16,777,216
  float* Qe   = (float*)(P4 + 16777216);                               // 16,777,216
  float* Obuf = (float*)(P4 + 33554432);                               // 16,777,216
  // P5 region (50,331,648): early = lwb; then Astk; then S0g (Astk dead)
  char* P5 = base + 109051904;
  float* lwb = (float*)(P5 + 0);                                       // 4,194,304
  __hip_bfloat16* Astk = (__hip_bfloat16*)P5;                          // 50,331,648
  float* S0g = (float*)P5;                                             // 16,777,216
  // P6: persistent small
  char* P6 = base + 159383552;
  float* betp  = (float*)(P6 + 0);                                     // 786,432
  float* decp  = (float*)(P6 + 786432);                                // 262,144
  float* lwcb  = (float*)(P6 + 1048576);                               // 65,536
  float* statb = (float*)(P6 + 1114112);                               // 1,024
  __hip_bfloat16* Wob = (__hip_bfloat16*)(P6 + 1115136);               // 2,097,152
  __hip_bfloat16* ogb = (__hip_bfloat16*)(P6 + 3212288);               // 8,388,608
  double* gnpart = (double*)(base + 170984448);                        // 16,384

  const dim3 blk(256);

  // fused casts (x + all weights + bd pack)
  cast_all<<<dim3(14080), blk, 0, stream>>>(x, Wq, Wk, Wv, Wg, Wl, Wo, Wb, Wa,
                                            xb, Wqb, Wkb, Wvb, Wgb, Wlb, Wob, Wbdb);

  // all six input projections in one dispatch
  gemm_fused<<<dim3(2144), blk, 0, stream>>>(xb, Wqb, Wkb, Wvb, Wbdb, Wlb, Wgb,
                                             qpack, KP16, VP16, betp, decp, lwb, ogb, Lp);

  lwc_mean<<<dim3(64), blk, 0, stream>>>(lwb, lwcb);

  // chunk operators
  gram_phi<<<dim3(1024), blk, 0, stream>>>(KP16, qpack, betp, G16, Astk);
  chunk_solve<<<dim3(1024, 2), blk, 0, stream>>>(G16, KP16, VP16, betp, decp);
  products<<<dim3(1024), blk, 0, stream>>>(Astk, KP16, VP16, qpack, decp,
                                           Tc, Qe, (float*)KP16, (float*)VP16);

  // sequential state scan (256 blocks) + parallel O gemm (+ fused gn partials)
  state_scan<<<dim3(256), blk, 0, stream>>>(Tc, (const float*)KP16, lwcb, S0g);
  o_gemm<<<dim3(1024), blk, 0, stream>>>(Qe, S0g, (const float*)VP16, Obuf, gnpart);

  // group norm + gate
  gn_stats2<<<dim3(1), dim3(64), 0, stream>>>(gnpart, statb);
  gate_kernel<<<dim3((kM * 1024 + 255) / 256), blk, 0, stream>>>(Obuf, ogb, gamma, gbeta,
                                                                 statb, zbf);

  // final projection
  gemm_out<<<dim3(8, 32), blk, 0, stream>>>(zbf, Wob, out);
}